// Round 20
// baseline (1045.123 us; speedup 1.0000x reference)
//
#include <hip/hip_runtime.h>
#include <hip/hip_bf16.h>

#define N_NODES 50000
#define N_EDGES 800000
#define NUM_MOL 2000

typedef __attribute__((ext_vector_type(8))) short short8;
typedef __attribute__((ext_vector_type(4))) float f32x4;

union bfbits { __hip_bfloat16 b; short s; };

// ---------------------------------------------------------------------------
// Type tables.
// ---------------------------------------------------------------------------
__global__ void k_tables(const float* __restrict__ atom_table,
                         const float* __restrict__ bond_table,
                         const float* __restrict__ Wi,
                         const float* __restrict__ bi,
                         const float* __restrict__ Wu1,
                         const float* __restrict__ bu1,
                         float* __restrict__ T1, float* __restrict__ U1,
                         float* __restrict__ T2c, float* __restrict__ U2c) {
  int b = blockIdx.x;
  int c = threadIdx.x;
  if (b < 119) {
    float t = 0.f, u = 0.f;
    for (int k = 0; k < 128; k++) {
      float a = atom_table[b * 128 + k];
      t += a * Wi[k * 128 + c];
      u += a * Wu1[k * 128 + c];
    }
    T1[b * 128 + c] = t;
    U1[b * 128 + c] = u;
  } else {
    int a = b - 119;
    float t = bi[c], u = bu1[c];
    for (int k = 0; k < 64; k++) {
      float bv = bond_table[a * 64 + k];
      t += bv * Wi[(128 + k) * 128 + c];
      u += bv * Wu1[(128 + k) * 128 + c];
    }
    T2c[a * 128 + c] = t;
    U2c[a * 128 + c] = u;
  }
}

// Merged prep: b<476 -> TT rows; 476..603 -> Wt/Wlo; 604..731 -> W1t/W1lo.
__global__ void k_prep(const float* __restrict__ T1, const float* __restrict__ T2c,
                       const float* __restrict__ Wu2, const float* __restrict__ Wu1,
                       float* __restrict__ TT,
                       short* __restrict__ Wt, short* __restrict__ Wlo,
                       short* __restrict__ W1t, short* __restrict__ W1lo) {
  int b = blockIdx.x;
  int k = threadIdx.x;
  if (b < 476) {
    float v = T1[(b >> 2) * 128 + k] + T2c[(b & 3) * 128 + k];
    TT[b * 128 + k] = v > 0.f ? v : 0.f;
  } else if (b < 604) {
    int n = b - 476;
    float w = Wu2[k * 128 + n];
    bfbits hi; hi.b = __float2bfloat16(w);
    float hf = __bfloat162float(hi.b);
    bfbits lo; lo.b = __float2bfloat16(w - hf);
    Wt[n * 128 + k] = hi.s;
    Wlo[n * 128 + k] = lo.s;
  } else {
    int n = b - 604;
    float w = Wu1[(192 + k) * 128 + n];
    bfbits hi; hi.b = __float2bfloat16(w);
    float hf = __bfloat162float(hi.b);
    bfbits lo; lo.b = __float2bfloat16(w - hf);
    W1t[n * 128 + k] = hi.s;
    W1lo[n * 128 + k] = lo.s;
  }
}

// D_[n] = U1[x[n]]  -- pass-invariant.
__global__ void k_u1x(const int* __restrict__ x, const float* __restrict__ U1,
                      float* __restrict__ D_) {
  int n = blockIdx.x * 4 + (threadIdx.x >> 6);
  int lane = threadIdx.x & 63;
  int xn = x[n];
  float2 v = *(const float2*)&U1[xn * 128 + lane * 2];
  *(float2*)&D_[n * 128 + lane * 2] = v;
}

// ---------------------------------------------------------------------------
// Padded-bucket CSR: csr[d*64 + pos], pos = atomicAdd(cnt[d],1).
// packed = (s*4+a) | ((x[s]*4+a) << 18)
// ---------------------------------------------------------------------------
__global__ void k_fillb(const int* __restrict__ eidx, const int* __restrict__ attr,
                        const int* __restrict__ x,
                        int* __restrict__ cnt, int* __restrict__ csr1) {
  int e = blockIdx.x * 256 + threadIdx.x;
  int d = eidx[N_EDGES + e];
  int s = eidx[e];
  int a = attr[e];
  int pos = atomicAdd(&cnt[d], 1);
  if (pos < 64) {
    int packed = (s * 4 + a) | ((x[s] * 4 + a) << 18);
    __builtin_nontemporal_store(packed, &csr1[d * 64 + pos]);
  }
}

// molptr[m] = lower_bound(batch, m)
__global__ void k_molptr(const int* __restrict__ batch, int* __restrict__ molptr) {
  int m = blockIdx.x * 256 + threadIdx.x;
  if (m > NUM_MOL) return;
  int lo = 0, hi = N_NODES;
  while (lo < hi) {
    int mid = (lo + hi) >> 1;
    if (batch[mid] < m) lo = mid + 1; else hi = mid;
  }
  molptr[m] = lo;
}

// ---------------------------------------------------------------------------
// Gather initial messages: 8 edges per iter (4 broadcast idx loads, 4 row
// loads in flight per lane pair-group). idx = pk >> 18
// ---------------------------------------------------------------------------
__global__ void k_gather0(const int* __restrict__ cnt, const int* __restrict__ csr1,
                          const float* __restrict__ TT, float* __restrict__ A_) {
  int n = blockIdx.x * 4 + (threadIdx.x >> 6);
  int lane = threadIdx.x & 63;
  int g = lane >> 5;        // 0..1
  int p = lane & 31;        // channel quad
  int beg = n * 64;
  int end = beg + cnt[n];
  float s0 = 0.f, s1 = 0.f, s2 = 0.f, s3 = 0.f;
  int i = beg;
  for (; i + 7 < end; i += 8) {
    int iA = ((unsigned)csr1[i + g]) >> 18;
    int iB = ((unsigned)csr1[i + 2 + g]) >> 18;
    int iC = ((unsigned)csr1[i + 4 + g]) >> 18;
    int iD = ((unsigned)csr1[i + 6 + g]) >> 18;
    float4 va = *(const float4*)&TT[iA * 128 + p * 4];
    float4 vb = *(const float4*)&TT[iB * 128 + p * 4];
    float4 vc = *(const float4*)&TT[iC * 128 + p * 4];
    float4 vd = *(const float4*)&TT[iD * 128 + p * 4];
    s0 += (va.x + vb.x) + (vc.x + vd.x);
    s1 += (va.y + vb.y) + (vc.y + vd.y);
    s2 += (va.z + vb.z) + (vc.z + vd.z);
    s3 += (va.w + vb.w) + (vc.w + vd.w);
  }
  for (; i + 3 < end; i += 4) {
    int iA = ((unsigned)csr1[i + g]) >> 18;
    int iB = ((unsigned)csr1[i + 2 + g]) >> 18;
    float4 va = *(const float4*)&TT[iA * 128 + p * 4];
    float4 vb = *(const float4*)&TT[iB * 128 + p * 4];
    s0 += va.x + vb.x; s1 += va.y + vb.y;
    s2 += va.z + vb.z; s3 += va.w + vb.w;
  }
  for (; i < end; i += 2) {
    if (i + g < end) {
      int idx = ((unsigned)csr1[i + g]) >> 18;
      float4 v = *(const float4*)&TT[idx * 128 + p * 4];
      s0 += v.x; s1 += v.y; s2 += v.z; s3 += v.w;
    }
  }
  s0 += __shfl_xor(s0, 32, 64);
  s1 += __shfl_xor(s1, 32, 64);
  s2 += __shfl_xor(s2, 32, 64);
  s3 += __shfl_xor(s3, 32, 64);
  float2 o;
  o.x = (g == 0) ? s0 : s2;
  o.y = (g == 0) ? s1 : s3;
  *(float2*)&A_[n * 128 + p * 4 + g * 2] = o;
}

// ---------------------------------------------------------------------------
// Gather messages: 16 edges per iter (4 broadcast idx loads, 4 row loads in
// flight per lane). idx = pk & 0x3FFFF
// ---------------------------------------------------------------------------
__global__ void k_gather(const int* __restrict__ cnt, const int* __restrict__ csr1,
                         const __hip_bfloat16* __restrict__ M, float* __restrict__ A_) {
  int n = blockIdx.x * 4 + (threadIdx.x >> 6);
  int lane = threadIdx.x & 63;
  int g = lane >> 4;        // 0..3
  int p = lane & 15;        // channel octet
  int beg = n * 64;
  int end = beg + cnt[n];
  float s[8];
#pragma unroll
  for (int j = 0; j < 8; j++) s[j] = 0.f;
  const short* Ms = (const short*)M;
  int i = beg;
  for (; i + 15 < end; i += 16) {
    int iA = csr1[i + g] & 0x3FFFF;
    int iB = csr1[i + 4 + g] & 0x3FFFF;
    int iC = csr1[i + 8 + g] & 0x3FFFF;
    int iD = csr1[i + 12 + g] & 0x3FFFF;
    short8 va = *(const short8*)&Ms[iA * 128 + p * 8];
    short8 vb = *(const short8*)&Ms[iB * 128 + p * 8];
    short8 vc = *(const short8*)&Ms[iC * 128 + p * 8];
    short8 vd = *(const short8*)&Ms[iD * 128 + p * 8];
#pragma unroll
    for (int j = 0; j < 4; j++) {
      float2 fa = __bfloat1622float2(*(const __hip_bfloat162*)&((const short*)&va)[j * 2]);
      float2 fb = __bfloat1622float2(*(const __hip_bfloat162*)&((const short*)&vb)[j * 2]);
      float2 fc = __bfloat1622float2(*(const __hip_bfloat162*)&((const short*)&vc)[j * 2]);
      float2 fd = __bfloat1622float2(*(const __hip_bfloat162*)&((const short*)&vd)[j * 2]);
      s[j * 2] += (fa.x + fb.x) + (fc.x + fd.x);
      s[j * 2 + 1] += (fa.y + fb.y) + (fc.y + fd.y);
    }
  }
  for (; i + 7 < end; i += 8) {
    int iA = csr1[i + g] & 0x3FFFF;
    int iB = csr1[i + 4 + g] & 0x3FFFF;
    short8 va = *(const short8*)&Ms[iA * 128 + p * 8];
    short8 vb = *(const short8*)&Ms[iB * 128 + p * 8];
#pragma unroll
    for (int j = 0; j < 4; j++) {
      float2 fa = __bfloat1622float2(*(const __hip_bfloat162*)&((const short*)&va)[j * 2]);
      float2 fb = __bfloat1622float2(*(const __hip_bfloat162*)&((const short*)&vb)[j * 2]);
      s[j * 2] += fa.x + fb.x;
      s[j * 2 + 1] += fa.y + fb.y;
    }
  }
  for (; i < end; i += 4) {
    if (i + g < end) {
      int idx = csr1[i + g] & 0x3FFFF;
      short8 va = *(const short8*)&Ms[idx * 128 + p * 8];
#pragma unroll
      for (int j = 0; j < 4; j++) {
        float2 fa = __bfloat1622float2(*(const __hip_bfloat162*)&((const short*)&va)[j * 2]);
        s[j * 2] += fa.x;
        s[j * 2 + 1] += fa.y;
      }
    }
  }
#pragma unroll
  for (int j = 0; j < 8; j++) s[j] += __shfl_xor(s[j], 16, 64);
#pragma unroll
  for (int j = 0; j < 8; j++) s[j] += __shfl_xor(s[j], 32, 64);
  float2 o;
  o.x = s[g * 2];
  o.y = s[g * 2 + 1];
  *(float2*)&A_[n * 128 + p * 8 + g * 2] = o;
}

// ---------------------------------------------------------------------------
// k_mm1m v3 (barrier-free MFMA, 4 waves/SIMD): wave-task = (slab, half).
// B2 = A@Wu1b + D. Private per-wave LDS transpose, no __syncthreads.
// 6250 tasks over 8192 waves (grid 2048).
// ---------------------------------------------------------------------------
__global__ __launch_bounds__(256, 4) void k_mm1m(const float* __restrict__ A_,
                                                 const short* __restrict__ W1t,
                                                 const short* __restrict__ W1lo,
                                                 const float* __restrict__ D_,
                                                 float* __restrict__ B2_) {
  __shared__ float mbuf[4][16][68];
  int t = threadIdx.x;
  int lane = t & 63;
  int m = lane & 15;
  int quad = lane >> 4;
  int wslot = t >> 6;
  int w0 = blockIdx.x * 4 + wslot;
  int h = w0 & 1;

  short8 whi[4][4], wlo[4][4];
#pragma unroll
  for (int kc = 0; kc < 4; kc++)
#pragma unroll
    for (int nt = 0; nt < 4; nt++) {
      int n = h * 64 + nt * 16 + m;
      whi[kc][nt] = *(const short8*)&W1t[n * 128 + kc * 32 + quad * 8];
      wlo[kc][nt] = *(const short8*)&W1lo[n * 128 + kc * 32 + quad * 8];
    }

  for (int tid = w0; tid < 6250; tid += 8192) {
    int s = tid >> 1;
    int row = s * 16 + m;
    f32x4 acc[4];
#pragma unroll
    for (int nt = 0; nt < 4; nt++) acc[nt] = (f32x4){0.f, 0.f, 0.f, 0.f};

#pragma unroll
    for (int kc = 0; kc < 4; kc++) {
      int k0 = kc * 32 + quad * 8;
      short8 ahi, alo;
      {
        float av[8];
        *(float4*)&av[0] = *(const float4*)&A_[row * 128 + k0];
        *(float4*)&av[4] = *(const float4*)&A_[row * 128 + k0 + 4];
#pragma unroll
        for (int j = 0; j < 8; j++) {
          float hv = av[j];
          bfbits hi; hi.b = __float2bfloat16(hv);
          float hf = __bfloat162float(hi.b);
          bfbits lo; lo.b = __float2bfloat16(hv - hf);
          ahi[j] = hi.s;
          alo[j] = lo.s;
        }
      }
#pragma unroll
      for (int nt = 0; nt < 4; nt++) {
        acc[nt] = __builtin_amdgcn_mfma_f32_16x16x32_bf16(ahi, whi[kc][nt], acc[nt], 0, 0, 0);
        acc[nt] = __builtin_amdgcn_mfma_f32_16x16x32_bf16(alo, whi[kc][nt], acc[nt], 0, 0, 0);
        acc[nt] = __builtin_amdgcn_mfma_f32_16x16x32_bf16(ahi, wlo[kc][nt], acc[nt], 0, 0, 0);
      }
    }

#pragma unroll
    for (int nt = 0; nt < 4; nt++)
#pragma unroll
      for (int r = 0; r < 4; r++)
        mbuf[wslot][quad * 4 + r][nt * 16 + m] = acc[nt][r];
#pragma unroll
    for (int p = 0; p < 4; p++) {
      int c = p * 64 + lane;
      int rr = c >> 4;
      int qf = c & 15;
      int n = s * 16 + rr;
      float4 v = *(const float4*)&mbuf[wslot][rr][qf * 4];
      float4 d = *(const float4*)&D_[n * 128 + h * 64 + qf * 4];
      v.x += d.x; v.y += d.y; v.z += d.z; v.w += d.w;
      *(float4*)&B2_[n * 128 + h * 64 + qf * 4] = v;
    }
  }
}

// ---------------------------------------------------------------------------
// k_mm2 v9 (barrier-free MFMA, 4 waves/SIMD): wave-task = (slab, half).
// H = relu(B2+U2c). Private per-wave LDS transpose, no __syncthreads.
// 25000 tasks over 8192 waves (grid 2048).
// ---------------------------------------------------------------------------
__global__ __launch_bounds__(256, 4) void k_mm2(const float* __restrict__ B2_,
                                                const float* __restrict__ U2c,
                                                const short* __restrict__ Wt,
                                                const short* __restrict__ Wlo,
                                                const float* __restrict__ bu2,
                                                __hip_bfloat16* __restrict__ M) {
  __shared__ short mbuf[4][16][68];
  int t = threadIdx.x;
  int lane = t & 63;
  int m = lane & 15;
  int quad = lane >> 4;
  int wslot = t >> 6;
  int w0 = blockIdx.x * 4 + wslot;
  int h = w0 & 1;

  short8 whi[4][4], wlo[4][4];
#pragma unroll
  for (int kc = 0; kc < 4; kc++)
#pragma unroll
    for (int nt = 0; nt < 4; nt++) {
      int n = h * 64 + nt * 16 + m;
      whi[kc][nt] = *(const short8*)&Wt[n * 128 + kc * 32 + quad * 8];
      wlo[kc][nt] = *(const short8*)&Wlo[n * 128 + kc * 32 + quad * 8];
    }
  float bias[4];
#pragma unroll
  for (int nt = 0; nt < 4; nt++) bias[nt] = bu2[h * 64 + nt * 16 + m];

  for (int tid = w0; tid < 25000; tid += 8192) {
    int s = tid >> 1;
    int node = s * 4 + (m >> 2);
    int attr = m & 3;
    f32x4 acc[4];
#pragma unroll
    for (int nt = 0; nt < 4; nt++) acc[nt] = (f32x4){0.f, 0.f, 0.f, 0.f};

#pragma unroll
    for (int kc = 0; kc < 4; kc++) {
      int k0 = kc * 32 + quad * 8;
      short8 ahi, alo;
      {
        float bba[8], u2a[8];
        *(float4*)&bba[0] = *(const float4*)&B2_[node * 128 + k0];
        *(float4*)&bba[4] = *(const float4*)&B2_[node * 128 + k0 + 4];
        *(float4*)&u2a[0] = *(const float4*)&U2c[attr * 128 + k0];
        *(float4*)&u2a[4] = *(const float4*)&U2c[attr * 128 + k0 + 4];
#pragma unroll
        for (int j = 0; j < 8; j++) {
          float hv = bba[j] + u2a[j];
          hv = hv > 0.f ? hv : 0.f;
          bfbits hi; hi.b = __float2bfloat16(hv);
          float hf = __bfloat162float(hi.b);
          bfbits lo; lo.b = __float2bfloat16(hv - hf);
          ahi[j] = hi.s;
          alo[j] = lo.s;
        }
      }
#pragma unroll
      for (int nt = 0; nt < 4; nt++) {
        acc[nt] = __builtin_amdgcn_mfma_f32_16x16x32_bf16(ahi, whi[kc][nt], acc[nt], 0, 0, 0);
        acc[nt] = __builtin_amdgcn_mfma_f32_16x16x32_bf16(alo, whi[kc][nt], acc[nt], 0, 0, 0);
        acc[nt] = __builtin_amdgcn_mfma_f32_16x16x32_bf16(ahi, wlo[kc][nt], acc[nt], 0, 0, 0);
      }
    }

#pragma unroll
    for (int nt = 0; nt < 4; nt++) {
#pragma unroll
      for (int r = 0; r < 4; r++) {
        float v = acc[nt][r] + bias[nt];
        v = v > 0.f ? v : 0.f;
        bfbits o; o.b = __float2bfloat16(v);
        mbuf[wslot][quad * 4 + r][nt * 16 + m] = o.s;
      }
    }
    {
      int rr = lane >> 2;
      int qq = lane & 3;
      short8 v = *(const short8*)&mbuf[wslot][rr][qq * 8];
      *(short8*)((short*)M + (s * 16 + rr) * 128 + h * 64 + qq * 8) = v;
      short8 v2 = *(const short8*)&mbuf[wslot][rr][(qq + 4) * 8];
      *(short8*)((short*)M + (s * 16 + rr) * 128 + h * 64 + (qq + 4) * 8) = v2;
    }
  }
}

// ---------------------------------------------------------------------------
// mol[m] = sum of A rows in [molptr[m], molptr[m+1]) — one wave per mol.
// ---------------------------------------------------------------------------
__global__ void k_molgather(const float* __restrict__ A_, const int* __restrict__ molptr,
                            float* __restrict__ mol) {
  int m = blockIdx.x * 4 + (threadIdx.x >> 6);
  int lane = threadIdx.x & 63;
  int beg = molptr[m], end = molptr[m + 1];
  float ax = 0.f, ay = 0.f;
  int n = beg;
  for (; n + 1 < end; n += 2) {
    float2 v0 = *(const float2*)&A_[n * 128 + lane * 2];
    float2 v1 = *(const float2*)&A_[(n + 1) * 128 + lane * 2];
    ax += v0.x + v1.x;
    ay += v0.y + v1.y;
  }
  if (n < end) {
    float2 v0 = *(const float2*)&A_[n * 128 + lane * 2];
    ax += v0.x;
    ay += v0.y;
  }
  float2 o; o.x = ax; o.y = ay;
  *(float2*)&mol[m * 128 + lane * 2] = o;
}

// ---------------------------------------------------------------------------
// out[m] = relu(mol[m] @ Wr1 + br1) @ Wr2 + br2
// ---------------------------------------------------------------------------
__global__ __launch_bounds__(256) void k_readout(const float* __restrict__ mol,
                                                 const float* __restrict__ Wr1,
                                                 const float* __restrict__ br1,
                                                 const float* __restrict__ Wr2,
                                                 const float* __restrict__ br2,
                                                 float* __restrict__ out) {
  int m = blockIdx.x;
  __shared__ float ms[128];
  __shared__ float red[256];
  int t = threadIdx.x;
  if (t < 128) ms[t] = mol[m * 128 + t];
  __syncthreads();
  float part = 0.f;
#pragma unroll
  for (int jj = 0; jj < 2; jj++) {
    int j = t + jj * 256;
    float acc = br1[j];
#pragma unroll
    for (int k = 0; k < 128; k += 4) {
      float4 m4 = *(const float4*)&ms[k];
      acc += m4.x * Wr1[k * 512 + j] + m4.y * Wr1[(k + 1) * 512 + j] +
             m4.z * Wr1[(k + 2) * 512 + j] + m4.w * Wr1[(k + 3) * 512 + j];
    }
    acc = acc > 0.f ? acc : 0.f;
    part += acc * Wr2[j];
  }
  red[t] = part;
  __syncthreads();
  for (int s = 128; s > 0; s >>= 1) {
    if (t < s) red[t] += red[t + s];
    __syncthreads();
  }
  if (t == 0) out[m] = red[0] + br2[0];
}

// ---------------------------------------------------------------------------
extern "C" void kernel_launch(void* const* d_in, const int* in_sizes, int n_in,
                              void* d_out, int out_size, void* d_ws, size_t ws_size,
                              hipStream_t stream) {
  const int* x        = (const int*)d_in[0];
  const int* eattr    = (const int*)d_in[1];
  const int* eidx     = (const int*)d_in[2];
  const int* batch    = (const int*)d_in[3];
  const float* atom_table = (const float*)d_in[4];
  const float* bond_table = (const float*)d_in[5];
  const float* Wi  = (const float*)d_in[6];
  const float* bi  = (const float*)d_in[7];
  const float* Wu1 = (const float*)d_in[8];
  const float* bu1 = (const float*)d_in[9];
  const float* Wu2 = (const float*)d_in[10];
  const float* bu2 = (const float*)d_in[11];
  const float* Wr1 = (const float*)d_in[12];
  const float* br1 = (const float*)d_in[13];
  const float* Wr2 = (const float*)d_in[14];
  const float* br2 = (const float*)d_in[15];
  float* out = (float*)d_out;

  char* ws = (char*)d_ws;
  __hip_bfloat16* M = (__hip_bfloat16*)(ws);       //  51,200,000 B (bf16)
  short* Wt      = (short*)(ws + 51200000);        //      32,768 B
  short* Wlo     = (short*)(ws + 51232768);        //      32,768 B
  short* W1t     = (short*)(ws + 51265536);        //      32,768 B
  short* W1lo    = (short*)(ws + 51298304);        //      32,768 B
  int*   molptr  = (int*)  (ws + 51331072);        //       8,004 B
  int*   cnt     = (int*)  (ws + 51340000);        //     200,000 B
  int*   csr1    = (int*)  (ws + 52000000);        //  12,800,000 B (64-slot buckets)
  float* D       = (float*)(ws + 65000000);        //  25,600,000 B (U1[x[n]])
  float* A       = (float*)(ws + 102400000);       //  25,600,000 B
  float* B2      = (float*)(ws + 128000000);       //  25,600,000 B
  float* T1      = (float*)(ws + 157000064);       //      60,928 B
  float* U1      = (float*)(ws + 157060992);       //      60,928 B
  float* T2c     = (float*)(ws + 157121920);       //       2,048 B
  float* U2c     = (float*)(ws + 157123968);       //       2,048 B
  float* TT      = (float*)(ws + 157126016);       //     243,712 B
  float* mol     = (float*)(ws + 157369728);       //   1,024,000 B

  hipMemsetAsync(cnt, 0, N_NODES * sizeof(int), stream);
  k_tables<<<123, 128, 0, stream>>>(atom_table, bond_table, Wi, bi, Wu1, bu1,
                                    T1, U1, T2c, U2c);
  k_prep<<<732, 128, 0, stream>>>(T1, T2c, Wu2, Wu1, TT, Wt, Wlo, W1t, W1lo);
  k_u1x<<<N_NODES / 4, 256, 0, stream>>>(x, U1, D);
  k_fillb<<<N_EDGES / 256, 256, 0, stream>>>(eidx, eattr, x, cnt, csr1);
  k_molptr<<<(NUM_MOL + 256) / 256, 256, 0, stream>>>(batch, molptr);

  k_gather0<<<N_NODES / 4, 256, 0, stream>>>(cnt, csr1, TT, A);

  for (int p = 0; p < 4; p++) {
    k_mm1m<<<2048, 256, 0, stream>>>(A, W1t, W1lo, D, B2);
    k_mm2<<<2048, 256, 0, stream>>>(B2, U2c, Wt, Wlo, bu2, M);
    k_gather<<<N_NODES / 4, 256, 0, stream>>>(cnt, csr1, M, A);
  }

  k_molgather<<<NUM_MOL / 4, 256, 0, stream>>>(A, molptr, mol);
  k_readout<<<NUM_MOL, 256, 0, stream>>>(mol, Wr1, br1, Wr2, br2, out);
}

// Round 21
// 641.394 us; speedup vs baseline: 1.6295x; 1.6295x over previous
//
#include <hip/hip_runtime.h>
#include <hip/hip_bf16.h>

#define N_NODES 50000
#define N_EDGES 800000
#define NUM_MOL 2000

typedef __attribute__((ext_vector_type(8))) short short8;
typedef __attribute__((ext_vector_type(4))) float f32x4;

union bfbits { __hip_bfloat16 b; short s; };

// ---------------------------------------------------------------------------
// Type tables.
// ---------------------------------------------------------------------------
__global__ void k_tables(const float* __restrict__ atom_table,
                         const float* __restrict__ bond_table,
                         const float* __restrict__ Wi,
                         const float* __restrict__ bi,
                         const float* __restrict__ Wu1,
                         const float* __restrict__ bu1,
                         float* __restrict__ T1, float* __restrict__ U1,
                         float* __restrict__ T2c, float* __restrict__ U2c) {
  int b = blockIdx.x;
  int c = threadIdx.x;
  if (b < 119) {
    float t = 0.f, u = 0.f;
    for (int k = 0; k < 128; k++) {
      float a = atom_table[b * 128 + k];
      t += a * Wi[k * 128 + c];
      u += a * Wu1[k * 128 + c];
    }
    T1[b * 128 + c] = t;
    U1[b * 128 + c] = u;
  } else {
    int a = b - 119;
    float t = bi[c], u = bu1[c];
    for (int k = 0; k < 64; k++) {
      float bv = bond_table[a * 64 + k];
      t += bv * Wi[(128 + k) * 128 + c];
      u += bv * Wu1[(128 + k) * 128 + c];
    }
    T2c[a * 128 + c] = t;
    U2c[a * 128 + c] = u;
  }
}

// Merged prep: b<476 -> TT rows; 476..603 -> Wt/Wlo; 604..731 -> W1t/W1lo.
__global__ void k_prep(const float* __restrict__ T1, const float* __restrict__ T2c,
                       const float* __restrict__ Wu2, const float* __restrict__ Wu1,
                       float* __restrict__ TT,
                       short* __restrict__ Wt, short* __restrict__ Wlo,
                       short* __restrict__ W1t, short* __restrict__ W1lo) {
  int b = blockIdx.x;
  int k = threadIdx.x;
  if (b < 476) {
    float v = T1[(b >> 2) * 128 + k] + T2c[(b & 3) * 128 + k];
    TT[b * 128 + k] = v > 0.f ? v : 0.f;
  } else if (b < 604) {
    int n = b - 476;
    float w = Wu2[k * 128 + n];
    bfbits hi; hi.b = __float2bfloat16(w);
    float hf = __bfloat162float(hi.b);
    bfbits lo; lo.b = __float2bfloat16(w - hf);
    Wt[n * 128 + k] = hi.s;
    Wlo[n * 128 + k] = lo.s;
  } else {
    int n = b - 604;
    float w = Wu1[(192 + k) * 128 + n];
    bfbits hi; hi.b = __float2bfloat16(w);
    float hf = __bfloat162float(hi.b);
    bfbits lo; lo.b = __float2bfloat16(w - hf);
    W1t[n * 128 + k] = hi.s;
    W1lo[n * 128 + k] = lo.s;
  }
}

// D_[n] = U1[x[n]]  -- pass-invariant.
__global__ void k_u1x(const int* __restrict__ x, const float* __restrict__ U1,
                      float* __restrict__ D_) {
  int n = blockIdx.x * 4 + (threadIdx.x >> 6);
  int lane = threadIdx.x & 63;
  int xn = x[n];
  float2 v = *(const float2*)&U1[xn * 128 + lane * 2];
  *(float2*)&D_[n * 128 + lane * 2] = v;
}

// ---------------------------------------------------------------------------
// Padded-bucket CSR: csr[d*64 + pos], pos = atomicAdd(cnt[d],1).
// packed = (s*4+a) | ((x[s]*4+a) << 18)
// ---------------------------------------------------------------------------
__global__ void k_fillb(const int* __restrict__ eidx, const int* __restrict__ attr,
                        const int* __restrict__ x,
                        int* __restrict__ cnt, int* __restrict__ csr1) {
  int e = blockIdx.x * 256 + threadIdx.x;
  int d = eidx[N_EDGES + e];
  int s = eidx[e];
  int a = attr[e];
  int pos = atomicAdd(&cnt[d], 1);
  if (pos < 64) {
    int packed = (s * 4 + a) | ((x[s] * 4 + a) << 18);
    __builtin_nontemporal_store(packed, &csr1[d * 64 + pos]);
  }
}

// molptr[m] = lower_bound(batch, m)
__global__ void k_molptr(const int* __restrict__ batch, int* __restrict__ molptr) {
  int m = blockIdx.x * 256 + threadIdx.x;
  if (m > NUM_MOL) return;
  int lo = 0, hi = N_NODES;
  while (lo < hi) {
    int mid = (lo + hi) >> 1;
    if (batch[mid] < m) lo = mid + 1; else hi = mid;
  }
  molptr[m] = lo;
}

// ---------------------------------------------------------------------------
// Gather initial messages: 8 edges per iter. idx = pk >> 18
// ---------------------------------------------------------------------------
__global__ void k_gather0(const int* __restrict__ cnt, const int* __restrict__ csr1,
                          const float* __restrict__ TT, float* __restrict__ A_) {
  int n = blockIdx.x * 4 + (threadIdx.x >> 6);
  int lane = threadIdx.x & 63;
  int g = lane >> 5;        // 0..1
  int p = lane & 31;        // channel quad
  int beg = n * 64;
  int end = beg + cnt[n];
  float s0 = 0.f, s1 = 0.f, s2 = 0.f, s3 = 0.f;
  int i = beg;
  for (; i + 7 < end; i += 8) {
    int iA = ((unsigned)csr1[i + g]) >> 18;
    int iB = ((unsigned)csr1[i + 2 + g]) >> 18;
    int iC = ((unsigned)csr1[i + 4 + g]) >> 18;
    int iD = ((unsigned)csr1[i + 6 + g]) >> 18;
    float4 va = *(const float4*)&TT[iA * 128 + p * 4];
    float4 vb = *(const float4*)&TT[iB * 128 + p * 4];
    float4 vc = *(const float4*)&TT[iC * 128 + p * 4];
    float4 vd = *(const float4*)&TT[iD * 128 + p * 4];
    s0 += (va.x + vb.x) + (vc.x + vd.x);
    s1 += (va.y + vb.y) + (vc.y + vd.y);
    s2 += (va.z + vb.z) + (vc.z + vd.z);
    s3 += (va.w + vb.w) + (vc.w + vd.w);
  }
  for (; i + 3 < end; i += 4) {
    int iA = ((unsigned)csr1[i + g]) >> 18;
    int iB = ((unsigned)csr1[i + 2 + g]) >> 18;
    float4 va = *(const float4*)&TT[iA * 128 + p * 4];
    float4 vb = *(const float4*)&TT[iB * 128 + p * 4];
    s0 += va.x + vb.x; s1 += va.y + vb.y;
    s2 += va.z + vb.z; s3 += va.w + vb.w;
  }
  for (; i < end; i += 2) {
    if (i + g < end) {
      int idx = ((unsigned)csr1[i + g]) >> 18;
      float4 v = *(const float4*)&TT[idx * 128 + p * 4];
      s0 += v.x; s1 += v.y; s2 += v.z; s3 += v.w;
    }
  }
  s0 += __shfl_xor(s0, 32, 64);
  s1 += __shfl_xor(s1, 32, 64);
  s2 += __shfl_xor(s2, 32, 64);
  s3 += __shfl_xor(s3, 32, 64);
  float2 o;
  o.x = (g == 0) ? s0 : s2;
  o.y = (g == 0) ? s1 : s3;
  *(float2*)&A_[n * 128 + p * 4 + g * 2] = o;
}

// ---------------------------------------------------------------------------
// Gather messages: 16 edges per iter. idx = pk & 0x3FFFF
// ---------------------------------------------------------------------------
__global__ void k_gather(const int* __restrict__ cnt, const int* __restrict__ csr1,
                         const __hip_bfloat16* __restrict__ M, float* __restrict__ A_) {
  int n = blockIdx.x * 4 + (threadIdx.x >> 6);
  int lane = threadIdx.x & 63;
  int g = lane >> 4;        // 0..3
  int p = lane & 15;        // channel octet
  int beg = n * 64;
  int end = beg + cnt[n];
  float s[8];
#pragma unroll
  for (int j = 0; j < 8; j++) s[j] = 0.f;
  const short* Ms = (const short*)M;
  int i = beg;
  for (; i + 15 < end; i += 16) {
    int iA = csr1[i + g] & 0x3FFFF;
    int iB = csr1[i + 4 + g] & 0x3FFFF;
    int iC = csr1[i + 8 + g] & 0x3FFFF;
    int iD = csr1[i + 12 + g] & 0x3FFFF;
    short8 va = *(const short8*)&Ms[iA * 128 + p * 8];
    short8 vb = *(const short8*)&Ms[iB * 128 + p * 8];
    short8 vc = *(const short8*)&Ms[iC * 128 + p * 8];
    short8 vd = *(const short8*)&Ms[iD * 128 + p * 8];
#pragma unroll
    for (int j = 0; j < 4; j++) {
      float2 fa = __bfloat1622float2(*(const __hip_bfloat162*)&((const short*)&va)[j * 2]);
      float2 fb = __bfloat1622float2(*(const __hip_bfloat162*)&((const short*)&vb)[j * 2]);
      float2 fc = __bfloat1622float2(*(const __hip_bfloat162*)&((const short*)&vc)[j * 2]);
      float2 fd = __bfloat1622float2(*(const __hip_bfloat162*)&((const short*)&vd)[j * 2]);
      s[j * 2] += (fa.x + fb.x) + (fc.x + fd.x);
      s[j * 2 + 1] += (fa.y + fb.y) + (fc.y + fd.y);
    }
  }
  for (; i + 7 < end; i += 8) {
    int iA = csr1[i + g] & 0x3FFFF;
    int iB = csr1[i + 4 + g] & 0x3FFFF;
    short8 va = *(const short8*)&Ms[iA * 128 + p * 8];
    short8 vb = *(const short8*)&Ms[iB * 128 + p * 8];
#pragma unroll
    for (int j = 0; j < 4; j++) {
      float2 fa = __bfloat1622float2(*(const __hip_bfloat162*)&((const short*)&va)[j * 2]);
      float2 fb = __bfloat1622float2(*(const __hip_bfloat162*)&((const short*)&vb)[j * 2]);
      s[j * 2] += fa.x + fb.x;
      s[j * 2 + 1] += fa.y + fb.y;
    }
  }
  for (; i < end; i += 4) {
    if (i + g < end) {
      int idx = csr1[i + g] & 0x3FFFF;
      short8 va = *(const short8*)&Ms[idx * 128 + p * 8];
#pragma unroll
      for (int j = 0; j < 4; j++) {
        float2 fa = __bfloat1622float2(*(const __hip_bfloat162*)&((const short*)&va)[j * 2]);
        s[j * 2] += fa.x;
        s[j * 2 + 1] += fa.y;
      }
    }
  }
#pragma unroll
  for (int j = 0; j < 8; j++) s[j] += __shfl_xor(s[j], 16, 64);
#pragma unroll
  for (int j = 0; j < 8; j++) s[j] += __shfl_xor(s[j], 32, 64);
  float2 o;
  o.x = s[g * 2];
  o.y = s[g * 2 + 1];
  *(float2*)&A_[n * 128 + p * 8 + g * 2] = o;
}

// ---------------------------------------------------------------------------
// k_mm1m v2 (barrier-free MFMA, 2 waves/SIMD so weights stay in VGPRs):
// wave-task = (slab, half). B2 = A@Wu1b + D. Private per-wave LDS transpose.
// 6250 tasks over 4096 waves (grid 1024).
// ---------------------------------------------------------------------------
__global__ __launch_bounds__(256, 2) void k_mm1m(const float* __restrict__ A_,
                                                 const short* __restrict__ W1t,
                                                 const short* __restrict__ W1lo,
                                                 const float* __restrict__ D_,
                                                 float* __restrict__ B2_) {
  __shared__ float mbuf[4][16][68];
  int t = threadIdx.x;
  int lane = t & 63;
  int m = lane & 15;
  int quad = lane >> 4;
  int wslot = t >> 6;
  int w0 = blockIdx.x * 4 + wslot;
  int h = w0 & 1;

  short8 whi[4][4], wlo[4][4];
#pragma unroll
  for (int kc = 0; kc < 4; kc++)
#pragma unroll
    for (int nt = 0; nt < 4; nt++) {
      int n = h * 64 + nt * 16 + m;
      whi[kc][nt] = *(const short8*)&W1t[n * 128 + kc * 32 + quad * 8];
      wlo[kc][nt] = *(const short8*)&W1lo[n * 128 + kc * 32 + quad * 8];
    }

  for (int tid = w0; tid < 6250; tid += 4096) {
    int s = tid >> 1;
    int row = s * 16 + m;
    f32x4 acc[4];
#pragma unroll
    for (int nt = 0; nt < 4; nt++) acc[nt] = (f32x4){0.f, 0.f, 0.f, 0.f};

#pragma unroll
    for (int kc = 0; kc < 4; kc++) {
      int k0 = kc * 32 + quad * 8;
      short8 ahi, alo;
      {
        float av[8];
        *(float4*)&av[0] = *(const float4*)&A_[row * 128 + k0];
        *(float4*)&av[4] = *(const float4*)&A_[row * 128 + k0 + 4];
#pragma unroll
        for (int j = 0; j < 8; j++) {
          float hv = av[j];
          bfbits hi; hi.b = __float2bfloat16(hv);
          float hf = __bfloat162float(hi.b);
          bfbits lo; lo.b = __float2bfloat16(hv - hf);
          ahi[j] = hi.s;
          alo[j] = lo.s;
        }
      }
#pragma unroll
      for (int nt = 0; nt < 4; nt++) {
        acc[nt] = __builtin_amdgcn_mfma_f32_16x16x32_bf16(ahi, whi[kc][nt], acc[nt], 0, 0, 0);
        acc[nt] = __builtin_amdgcn_mfma_f32_16x16x32_bf16(alo, whi[kc][nt], acc[nt], 0, 0, 0);
        acc[nt] = __builtin_amdgcn_mfma_f32_16x16x32_bf16(ahi, wlo[kc][nt], acc[nt], 0, 0, 0);
      }
    }

#pragma unroll
    for (int nt = 0; nt < 4; nt++)
#pragma unroll
      for (int r = 0; r < 4; r++)
        mbuf[wslot][quad * 4 + r][nt * 16 + m] = acc[nt][r];
#pragma unroll
    for (int p = 0; p < 4; p++) {
      int c = p * 64 + lane;
      int rr = c >> 4;
      int qf = c & 15;
      int n = s * 16 + rr;
      float4 v = *(const float4*)&mbuf[wslot][rr][qf * 4];
      float4 d = *(const float4*)&D_[n * 128 + h * 64 + qf * 4];
      v.x += d.x; v.y += d.y; v.z += d.z; v.w += d.w;
      *(float4*)&B2_[n * 128 + h * 64 + qf * 4] = v;
    }
  }
}

// ---------------------------------------------------------------------------
// k_mm2 v8 (barrier-free MFMA, 2 waves/SIMD): wave-task = (slab, half).
// H = relu(B2+U2c). Private per-wave LDS transpose. 25000 tasks, grid 1024.
// ---------------------------------------------------------------------------
__global__ __launch_bounds__(256, 2) void k_mm2(const float* __restrict__ B2_,
                                                const float* __restrict__ U2c,
                                                const short* __restrict__ Wt,
                                                const short* __restrict__ Wlo,
                                                const float* __restrict__ bu2,
                                                __hip_bfloat16* __restrict__ M) {
  __shared__ short mbuf[4][16][68];
  int t = threadIdx.x;
  int lane = t & 63;
  int m = lane & 15;
  int quad = lane >> 4;
  int wslot = t >> 6;
  int w0 = blockIdx.x * 4 + wslot;
  int h = w0 & 1;

  short8 whi[4][4], wlo[4][4];
#pragma unroll
  for (int kc = 0; kc < 4; kc++)
#pragma unroll
    for (int nt = 0; nt < 4; nt++) {
      int n = h * 64 + nt * 16 + m;
      whi[kc][nt] = *(const short8*)&Wt[n * 128 + kc * 32 + quad * 8];
      wlo[kc][nt] = *(const short8*)&Wlo[n * 128 + kc * 32 + quad * 8];
    }
  float bias[4];
#pragma unroll
  for (int nt = 0; nt < 4; nt++) bias[nt] = bu2[h * 64 + nt * 16 + m];

  for (int tid = w0; tid < 25000; tid += 4096) {
    int s = tid >> 1;
    int node = s * 4 + (m >> 2);
    int attr = m & 3;
    f32x4 acc[4];
#pragma unroll
    for (int nt = 0; nt < 4; nt++) acc[nt] = (f32x4){0.f, 0.f, 0.f, 0.f};

#pragma unroll
    for (int kc = 0; kc < 4; kc++) {
      int k0 = kc * 32 + quad * 8;
      short8 ahi, alo;
      {
        float bba[8], u2a[8];
        *(float4*)&bba[0] = *(const float4*)&B2_[node * 128 + k0];
        *(float4*)&bba[4] = *(const float4*)&B2_[node * 128 + k0 + 4];
        *(float4*)&u2a[0] = *(const float4*)&U2c[attr * 128 + k0];
        *(float4*)&u2a[4] = *(const float4*)&U2c[attr * 128 + k0 + 4];
#pragma unroll
        for (int j = 0; j < 8; j++) {
          float hv = bba[j] + u2a[j];
          hv = hv > 0.f ? hv : 0.f;
          bfbits hi; hi.b = __float2bfloat16(hv);
          float hf = __bfloat162float(hi.b);
          bfbits lo; lo.b = __float2bfloat16(hv - hf);
          ahi[j] = hi.s;
          alo[j] = lo.s;
        }
      }
#pragma unroll
      for (int nt = 0; nt < 4; nt++) {
        acc[nt] = __builtin_amdgcn_mfma_f32_16x16x32_bf16(ahi, whi[kc][nt], acc[nt], 0, 0, 0);
        acc[nt] = __builtin_amdgcn_mfma_f32_16x16x32_bf16(alo, whi[kc][nt], acc[nt], 0, 0, 0);
        acc[nt] = __builtin_amdgcn_mfma_f32_16x16x32_bf16(ahi, wlo[kc][nt], acc[nt], 0, 0, 0);
      }
    }

#pragma unroll
    for (int nt = 0; nt < 4; nt++) {
#pragma unroll
      for (int r = 0; r < 4; r++) {
        float v = acc[nt][r] + bias[nt];
        v = v > 0.f ? v : 0.f;
        bfbits o; o.b = __float2bfloat16(v);
        mbuf[wslot][quad * 4 + r][nt * 16 + m] = o.s;
      }
    }
    {
      int rr = lane >> 2;
      int qq = lane & 3;
      short8 v = *(const short8*)&mbuf[wslot][rr][qq * 8];
      *(short8*)((short*)M + (s * 16 + rr) * 128 + h * 64 + qq * 8) = v;
      short8 v2 = *(const short8*)&mbuf[wslot][rr][(qq + 4) * 8];
      *(short8*)((short*)M + (s * 16 + rr) * 128 + h * 64 + (qq + 4) * 8) = v2;
    }
  }
}

// ---------------------------------------------------------------------------
// mol[m] = sum of A rows in [molptr[m], molptr[m+1]) — one wave per mol.
// ---------------------------------------------------------------------------
__global__ void k_molgather(const float* __restrict__ A_, const int* __restrict__ molptr,
                            float* __restrict__ mol) {
  int m = blockIdx.x * 4 + (threadIdx.x >> 6);
  int lane = threadIdx.x & 63;
  int beg = molptr[m], end = molptr[m + 1];
  float ax = 0.f, ay = 0.f;
  int n = beg;
  for (; n + 1 < end; n += 2) {
    float2 v0 = *(const float2*)&A_[n * 128 + lane * 2];
    float2 v1 = *(const float2*)&A_[(n + 1) * 128 + lane * 2];
    ax += v0.x + v1.x;
    ay += v0.y + v1.y;
  }
  if (n < end) {
    float2 v0 = *(const float2*)&A_[n * 128 + lane * 2];
    ax += v0.x;
    ay += v0.y;
  }
  float2 o; o.x = ax; o.y = ay;
  *(float2*)&mol[m * 128 + lane * 2] = o;
}

// ---------------------------------------------------------------------------
// out[m] = relu(mol[m] @ Wr1 + br1) @ Wr2 + br2
// ---------------------------------------------------------------------------
__global__ __launch_bounds__(256) void k_readout(const float* __restrict__ mol,
                                                 const float* __restrict__ Wr1,
                                                 const float* __restrict__ br1,
                                                 const float* __restrict__ Wr2,
                                                 const float* __restrict__ br2,
                                                 float* __restrict__ out) {
  int m = blockIdx.x;
  __shared__ float ms[128];
  __shared__ float red[256];
  int t = threadIdx.x;
  if (t < 128) ms[t] = mol[m * 128 + t];
  __syncthreads();
  float part = 0.f;
#pragma unroll
  for (int jj = 0; jj < 2; jj++) {
    int j = t + jj * 256;
    float acc = br1[j];
#pragma unroll
    for (int k = 0; k < 128; k += 4) {
      float4 m4 = *(const float4*)&ms[k];
      acc += m4.x * Wr1[k * 512 + j] + m4.y * Wr1[(k + 1) * 512 + j] +
             m4.z * Wr1[(k + 2) * 512 + j] + m4.w * Wr1[(k + 3) * 512 + j];
    }
    acc = acc > 0.f ? acc : 0.f;
    part += acc * Wr2[j];
  }
  red[t] = part;
  __syncthreads();
  for (int s = 128; s > 0; s >>= 1) {
    if (t < s) red[t] += red[t + s];
    __syncthreads();
  }
  if (t == 0) out[m] = red[0] + br2[0];
}

// ---------------------------------------------------------------------------
extern "C" void kernel_launch(void* const* d_in, const int* in_sizes, int n_in,
                              void* d_out, int out_size, void* d_ws, size_t ws_size,
                              hipStream_t stream) {
  const int* x        = (const int*)d_in[0];
  const int* eattr    = (const int*)d_in[1];
  const int* eidx     = (const int*)d_in[2];
  const int* batch    = (const int*)d_in[3];
  const float* atom_table = (const float*)d_in[4];
  const float* bond_table = (const float*)d_in[5];
  const float* Wi  = (const float*)d_in[6];
  const float* bi  = (const float*)d_in[7];
  const float* Wu1 = (const float*)d_in[8];
  const float* bu1 = (const float*)d_in[9];
  const float* Wu2 = (const float*)d_in[10];
  const float* bu2 = (const float*)d_in[11];
  const float* Wr1 = (const float*)d_in[12];
  const float* br1 = (const float*)d_in[13];
  const float* Wr2 = (const float*)d_in[14];
  const float* br2 = (const float*)d_in[15];
  float* out = (float*)d_out;

  char* ws = (char*)d_ws;
  __hip_bfloat16* M = (__hip_bfloat16*)(ws);       //  51,200,000 B (bf16)
  short* Wt      = (short*)(ws + 51200000);        //      32,768 B
  short* Wlo     = (short*)(ws + 51232768);        //      32,768 B
  short* W1t     = (short*)(ws + 51265536);        //      32,768 B
  short* W1lo    = (short*)(ws + 51298304);        //      32,768 B
  int*   molptr  = (int*)  (ws + 51331072);        //       8,004 B
  int*   cnt     = (int*)  (ws + 51340000);        //     200,000 B
  int*   csr1    = (int*)  (ws + 52000000);        //  12,800,000 B (64-slot buckets)
  float* D       = (float*)(ws + 65000000);        //  25,600,000 B (U1[x[n]])
  float* A       = (float*)(ws + 102400000);       //  25,600,000 B
  float* B2      = (float*)(ws + 128000000);       //  25,600,000 B
  float* T1      = (float*)(ws + 157000064);       //      60,928 B
  float* U1      = (float*)(ws + 157060992);       //      60,928 B
  float* T2c     = (float*)(ws + 157121920);       //       2,048 B
  float* U2c     = (float*)(ws + 157123968);       //       2,048 B
  float* TT      = (float*)(ws + 157126016);       //     243,712 B
  float* mol     = (float*)(ws + 157369728);       //   1,024,000 B

  hipMemsetAsync(cnt, 0, N_NODES * sizeof(int), stream);
  k_tables<<<123, 128, 0, stream>>>(atom_table, bond_table, Wi, bi, Wu1, bu1,
                                    T1, U1, T2c, U2c);
  k_prep<<<732, 128, 0, stream>>>(T1, T2c, Wu2, Wu1, TT, Wt, Wlo, W1t, W1lo);
  k_u1x<<<N_NODES / 4, 256, 0, stream>>>(x, U1, D);
  k_fillb<<<N_EDGES / 256, 256, 0, stream>>>(eidx, eattr, x, cnt, csr1);
  k_molptr<<<(NUM_MOL + 256) / 256, 256, 0, stream>>>(batch, molptr);

  k_gather0<<<N_NODES / 4, 256, 0, stream>>>(cnt, csr1, TT, A);

  for (int p = 0; p < 4; p++) {
    k_mm1m<<<1024, 256, 0, stream>>>(A, W1t, W1lo, D, B2);
    k_mm2<<<1024, 256, 0, stream>>>(B2, U2c, Wt, Wlo, bu2, M);
    k_gather<<<N_NODES / 4, 256, 0, stream>>>(cnt, csr1, M, A);
  }

  k_molgather<<<NUM_MOL / 4, 256, 0, stream>>>(A, molptr, mol);
  k_readout<<<NUM_MOL, 256, 0, stream>>>(mol, Wr1, br1, Wr2, br2, out);
}